// Round 3
// baseline (313.115 us; speedup 1.0000x reference)
//
#include <hip/hip_runtime.h>

using f32x4 = __attribute__((ext_vector_type(4))) float;
using s16x8 = __attribute__((ext_vector_type(8))) short;
using u16x4 = __attribute__((ext_vector_type(4))) ushort;

constexpr int NB   = 16;    // batch
constexpr int CH   = 256;   // channels
constexpr int TT   = 4096;  // time
constexpr int NT   = 128;   // tokens per tile
constexpr int HALO = 8;     // (K-1)*DIL
constexpr int XROWS = NT + HALO;     // 136
constexpr int ROWB  = 512;           // bytes per LDS row (256 ch * 2B, swizzled)
constexpr int BUFB  = XROWS * ROWB;  // 69632 B per tile buffer

__device__ __forceinline__ ushort f2b(float f) {
    unsigned u; __builtin_memcpy(&u, &f, 4);
    u += 0x7FFFu + ((u >> 16) & 1u);   // RNE
    return (ushort)(u >> 16);
}
__device__ __forceinline__ float fast_sigmoid(float x) {
    return __builtin_amdgcn_rcpf(1.f + __expf(-x));
}
__device__ __forceinline__ float fast_tanh(float x) {
    return 2.f * __builtin_amdgcn_rcpf(1.f + __expf(-2.f * x)) - 1.f;
}
// XOR swizzle: row stride 512B == 0 (mod 128B); spread rows across the 8
// 16B slots of the bank array. Keeps 16B alignment (only bits 4..6 flip).
__device__ __forceinline__ int swz(int row, int colB) {
    return row * ROWB + (colB ^ ((row & 7) << 4));
}

// Weight prep: f32 -> bf16.
// W1[m][k]: m<256 filter / m>=256 gate, k = tap*256 + in_ch.
// W2[m][i]: m<256 res / m>=256 skip.
__global__ __launch_bounds__(512)
void prep_w(const float* __restrict__ wf, const float* __restrict__ wg,
            const float* __restrict__ wr, const float* __restrict__ wsk,
            ushort* __restrict__ W1, ushort* __restrict__ W2) {
    int g = blockIdx.x * 512 + threadIdx.x;
    if (g < 512 * 64) {                       // W1: 512 rows x 64 threads (4 i each)
        int m = g >> 6, i0 = (g & 63) * 4;
        const float* src = (m < 256) ? wf + ((size_t)m << 9)
                                     : wg + ((size_t)(m - 256) << 9);
        f32x4 a = *(const f32x4*)&src[i0 * 2];
        f32x4 c = *(const f32x4*)&src[i0 * 2 + 4];
        u16x4 t0v = { f2b(a[0]), f2b(a[2]), f2b(c[0]), f2b(c[2]) };
        u16x4 t1v = { f2b(a[1]), f2b(a[3]), f2b(c[1]), f2b(c[3]) };
        *(u16x4*)&W1[(size_t)m * 512 + i0]       = t0v;   // tap 0 block
        *(u16x4*)&W1[(size_t)m * 512 + 256 + i0] = t1v;   // tap 1 block
    } else {                                  // W2: 512 rows x 64 threads
        int g2 = g - 512 * 64;
        int m = g2 >> 6, i0 = (g2 & 63) * 4;
        const float* src = (m < 256) ? wr + ((size_t)m << 8)
                                     : wsk + ((size_t)(m - 256) << 8);
        f32x4 a = *(const f32x4*)&src[i0];
        u16x4 o = { f2b(a[0]), f2b(a[1]), f2b(a[2]), f2b(a[3]) };
        *(u16x4*)&W2[(size_t)m * 256 + i0] = o;
    }
}

// 256 blocks (1/CU) x 512 threads (8 waves, 2/SIMD). Each block runs TWO
// adjacent 128-token tiles with double-buffered LDS; tile-1's staging is
// issued chunk-wise inside tile-0's GEMM1 (issue-early / commit-late).
// W fragments use a 3-slot distance-2 prefetch ring so their vmcnt waits
// never drain younger in-flight staging loads (FIFO vmcnt semantics).
__global__ __launch_bounds__(512, 2)
void fused_block(const float* __restrict__ x,
                 const ushort* __restrict__ W1, const ushort* __restrict__ W2,
                 const float* __restrict__ b_filt, const float* __restrict__ b_gate,
                 const float* __restrict__ b_res,  const float* __restrict__ b_skip,
                 float* __restrict__ out) {
    __shared__ __align__(16) char lds[2 * BUFB];   // 139264 B -> 1 block/CU

    const int tid = threadIdx.x;
    const int b   = blockIdx.x >> 4;               // 16 blocks per batch row
    const int t0A = (blockIdx.x & 15) * (2 * NT);  // this block: tokens [t0A, t0A+256)
    const float* X = x + (size_t)b * CH * TT;

    // staging thread mapping (shared by prologue and pipelined stage)
    const int tc4 = tid & 3;          // token sub-chunk (4 tokens)
    const int cp  = tid >> 2;         // channel pair 0..127
    const float* Xa = X + (size_t)(cp * 2) * TT;
    const float* Xb = Xa + TT;
    const int tcl = tid & 255, thalf = tid >> 8;   // tail mapping

    // ---------------- prologue: stage tile 0 into buf0 ----------------
    {
        char* buf0 = lds;
        const int tg0 = t0A - HALO;
        #pragma unroll
        for (int it = 0; it < 8; ++it) {
            int tg = tg0 + it * 16 + tc4 * 4;
            f32x4 va = (f32x4){0.f,0.f,0.f,0.f}, vb = va;
            if (tg >= 0) { va = *(const f32x4*)&Xa[tg]; vb = *(const f32x4*)&Xb[tg]; }
            #pragma unroll
            for (int e = 0; e < 4; ++e) {
                int row = it * 16 + tc4 * 4 + e;
                unsigned pk = (unsigned)f2b(va[e]) | ((unsigned)f2b(vb[e]) << 16);
                *(unsigned*)(buf0 + swz(row, cp * 4)) = pk;
            }
        }
        f32x4 v = *(const f32x4*)&X[(size_t)tcl * TT + tg0 + 128 + thalf * 4];
        #pragma unroll
        for (int e = 0; e < 4; ++e)
            *(ushort*)(buf0 + swz(128 + thalf * 4 + e, tcl * 2)) = f2b(v[e]);
    }

    const int wv = tid >> 6, lane = tid & 63;
    const int l16 = lane & 15, quad = lane >> 4;
    // B-operand rows: cn 0/1 = filter ch, cn 2/3 = gate ch (paired with 0/1)
    int mrow[4];
    mrow[0] = wv * 32 + l16;        mrow[1] = wv * 32 + 16 + l16;
    mrow[2] = 256 + mrow[0];        mrow[3] = 256 + mrow[1];
    const ushort* W1p[4];
    #pragma unroll
    for (int cn = 0; cn < 4; ++cn)
        W1p[cn] = W1 + (size_t)mrow[cn] * 512 + quad * 8;

    __syncthreads();

    const size_t OUT1 = (size_t)NB * CH * TT;

#define ISSUE(c) do { \
        int _tg = tg0n + (c) * 16 + tc4 * 4; \
        ra[c] = *(const f32x4*)&Xa[_tg]; \
        rb[c] = *(const f32x4*)&Xb[_tg]; } while (0)
#define COMMIT(c) do { \
        _Pragma("unroll") \
        for (int _e = 0; _e < 4; ++_e) { \
            int _row = (c) * 16 + tc4 * 4 + _e; \
            unsigned _pk = (unsigned)f2b(ra[c][_e]) | ((unsigned)f2b(rb[c][_e]) << 16); \
            *(unsigned*)(bufN + swz(_row, cp * 4)) = _pk; } } while (0)
#define ISSUE_T() do { \
        rt = *(const f32x4*)&X[(size_t)tcl * TT + tg0n + 128 + thalf * 4]; } while (0)
#define COMMIT_T() do { \
        _Pragma("unroll") \
        for (int _e = 0; _e < 4; ++_e) \
            *(ushort*)(bufN + swz(128 + thalf * 4 + _e, tcl * 2)) = f2b(rt[_e]); } while (0)

    #pragma unroll
    for (int s = 0; s < 2; ++s) {
        char* buf  = lds + s * BUFB;
        char* bufN = lds + (s ^ 1) * BUFB;
        const int t0   = t0A + s * NT;
        const int tg0n = t0 + NT - HALO;   // next tile's stage base (>=120, no guard)

        f32x4 acc[8][4];
        #pragma unroll
        for (int i = 0; i < 8; ++i)
            #pragma unroll
            for (int j = 0; j < 4; ++j) acc[i][j] = (f32x4){0.f,0.f,0.f,0.f};

        f32x4 ra[8], rb[8], rt;            // staging chunks (s==0 only)

        // W1 prefetch ring: 3 slots, distance 2
        s16x8 w1r[3][4];
        #pragma unroll
        for (int cn = 0; cn < 4; ++cn) {
            w1r[0][cn] = *(const s16x8*)&W1p[cn][0];
            w1r[1][cn] = *(const s16x8*)&W1p[cn][32];
        }

        // -------- GEMM1 over K=512 (16 kq), staging tile s+1 when s==0 --------
        #pragma unroll
        for (int kq = 0; kq < 16; ++kq) {
            const int su = kq % 3, sl = (kq + 2) % 3;
            if (kq < 14) {
                #pragma unroll
                for (int cn = 0; cn < 4; ++cn)
                    w1r[sl][cn] = *(const s16x8*)&W1p[cn][(kq + 2) * 32];
            }
            if (s == 0) {
                if      (kq == 0)  { ISSUE(0); ISSUE(1); }
                else if (kq == 2)  { ISSUE(2); }
                else if (kq == 4)  { COMMIT(0); ISSUE(3); }
                else if (kq == 6)  { COMMIT(1); ISSUE(4); }
                else if (kq == 8)  { COMMIT(2); ISSUE(5); }
                else if (kq == 10) { COMMIT(3); ISSUE(6); }
                else if (kq == 12) { COMMIT(4); ISSUE(7); }
                else if (kq == 14) { COMMIT(5); ISSUE_T(); }
            }
            const int tap = kq >> 3, ci = kq & 7;
            #pragma unroll
            for (int g = 0; g < 4; ++g) {      // token-tiles in pairs (short xf live range)
                s16x8 xf0 = *(const s16x8*)(lds + s * BUFB
                              + swz((2*g) * 16 + l16 + 8 * tap, ci * 64 + quad * 16));
                s16x8 xf1 = *(const s16x8*)(lds + s * BUFB
                              + swz((2*g+1) * 16 + l16 + 8 * tap, ci * 64 + quad * 16));
                #pragma unroll
                for (int cn = 0; cn < 4; ++cn) {
                    acc[2*g][cn]   = __builtin_amdgcn_mfma_f32_16x16x32_bf16(xf0, w1r[su][cn], acc[2*g][cn],   0, 0, 0);
                    acc[2*g+1][cn] = __builtin_amdgcn_mfma_f32_16x16x32_bf16(xf1, w1r[su][cn], acc[2*g+1][cn], 0, 0, 0);
                }
            }
        }
        if (s == 0) { COMMIT(6); COMMIT(7); COMMIT_T(); }

        // W2 pointers + ring preload (latency hides under act)
        const ushort* W2p[4];
        #pragma unroll
        for (int cn = 0; cn < 4; ++cn)
            W2p[cn] = W2 + (size_t)mrow[cn] * 256 + quad * 8;
        s16x8 w2r[3][4];
        #pragma unroll
        for (int cn = 0; cn < 4; ++cn) {
            w2r[0][cn] = *(const s16x8*)&W2p[cn][0];
            w2r[1][cn] = *(const s16x8*)&W2p[cn][32];
        }

        __syncthreads();   // GEMM1 LDS reads + stage writes fenced

        // -------- activations -> z (bf16) rows 0..127 of buf --------
        #pragma unroll
        for (int cn = 0; cn < 2; ++cn) {
            const int zc = wv * 32 + cn * 16 + l16;
            const float bfv = b_filt[zc], bgv = b_gate[zc];
            #pragma unroll
            for (int tm = 0; tm < 8; ++tm) {
                #pragma unroll
                for (int r = 0; r < 4; ++r) {
                    float fv = acc[tm][cn][r]     + bfv;
                    float gv = acc[tm][cn + 2][r] + bgv;
                    int row = tm * 16 + quad * 4 + r;
                    *(ushort*)(buf + swz(row, zc * 2)) = f2b(fast_tanh(fv) * fast_sigmoid(gv));
                }
            }
        }
        __syncthreads();

        // -------- GEMM2 over K=256 (8 kq), reuse acc --------
        #pragma unroll
        for (int i = 0; i < 8; ++i)
            #pragma unroll
            for (int j = 0; j < 4; ++j) acc[i][j] = (f32x4){0.f,0.f,0.f,0.f};

        #pragma unroll
        for (int kq = 0; kq < 8; ++kq) {
            const int su = kq % 3, sl = (kq + 2) % 3;
            if (kq < 6) {
                #pragma unroll
                for (int cn = 0; cn < 4; ++cn)
                    w2r[sl][cn] = *(const s16x8*)&W2p[cn][(kq + 2) * 32];
            }
            #pragma unroll
            for (int g = 0; g < 4; ++g) {
                s16x8 zf0 = *(const s16x8*)(lds + s * BUFB
                              + swz((2*g) * 16 + l16, kq * 64 + quad * 16));
                s16x8 zf1 = *(const s16x8*)(lds + s * BUFB
                              + swz((2*g+1) * 16 + l16, kq * 64 + quad * 16));
                #pragma unroll
                for (int cn = 0; cn < 4; ++cn) {
                    acc[2*g][cn]   = __builtin_amdgcn_mfma_f32_16x16x32_bf16(zf0, w2r[su][cn], acc[2*g][cn],   0, 0, 0);
                    acc[2*g+1][cn] = __builtin_amdgcn_mfma_f32_16x16x32_bf16(zf1, w2r[su][cn], acc[2*g+1][cn], 0, 0, 0);
                }
            }
        }

        // -------- epilogue: nontemporal f32x4 stores --------
        #pragma unroll
        for (int cn = 0; cn < 2; ++cn) {
            const int ch = wv * 32 + cn * 16 + l16;
            const float br = b_res[ch], bs = b_skip[ch];
            const float* Xc = X + (size_t)ch * TT + t0;
            float* O0 = out + ((size_t)(b * CH + ch)) * TT + t0;
            float* O1 = O0 + OUT1;
            #pragma unroll
            for (int tm = 0; tm < 8; ++tm) {
                const int ttk = tm * 16 + quad * 4;
                f32x4 xv = *(const f32x4*)&Xc[ttk];   // exact f32 x (L2-hot)
                f32x4 o0, o1;
                #pragma unroll
                for (int r = 0; r < 4; ++r) {
                    o0[r] = xv[r] + acc[tm][cn][r] + br;
                    o1[r] = acc[tm][cn + 2][r] + bs;
                }
                __builtin_nontemporal_store(o0, (f32x4*)&O0[ttk]);
                __builtin_nontemporal_store(o1, (f32x4*)&O1[ttk]);
            }
        }
    }
#undef ISSUE
#undef COMMIT
#undef ISSUE_T
#undef COMMIT_T
}

extern "C" void kernel_launch(void* const* d_in, const int* in_sizes, int n_in,
                              void* d_out, int out_size, void* d_ws, size_t ws_size,
                              hipStream_t stream) {
    const float* x   = (const float*)d_in[0];
    const float* wf  = (const float*)d_in[1];
    const float* bfi = (const float*)d_in[2];
    const float* wg  = (const float*)d_in[3];
    const float* bg  = (const float*)d_in[4];
    const float* wr  = (const float*)d_in[5];
    const float* br  = (const float*)d_in[6];
    const float* wsk = (const float*)d_in[7];
    const float* bs  = (const float*)d_in[8];

    ushort* W1 = (ushort*)d_ws;                  // 512*512 bf16
    ushort* W2 = W1 + 512 * 512;                 // 512*256 bf16

    prep_w<<<128, 512, 0, stream>>>(wf, wg, wr, wsk, W1, W2);

    const int nBlocks = NB * (TT / NT) / 2;      // 256 (= CU count, 2 tiles/block)
    fused_block<<<nBlocks, 512, 0, stream>>>(x, W1, W2, bfi, bg, br, bs,
                                             (float*)d_out);
}

// Round 4
// 286.629 us; speedup vs baseline: 1.0924x; 1.0924x over previous
//
#include <hip/hip_runtime.h>

using f32x4 = __attribute__((ext_vector_type(4))) float;
using f32x2 = __attribute__((ext_vector_type(2))) float;
using s16x8 = __attribute__((ext_vector_type(8))) short;
using u16x4 = __attribute__((ext_vector_type(4))) ushort;

constexpr int NB   = 16;    // batch
constexpr int CH   = 256;   // channels
constexpr int TT   = 4096;  // time
constexpr int NT   = 128;   // tokens per tile
constexpr int HALO = 8;     // (K-1)*DIL
constexpr int XROWS = NT + HALO;     // 136
constexpr int ROWB  = 512;           // bytes per LDS row (256 ch * 2B, swizzled)

__device__ __forceinline__ ushort f2b(float f) {
    unsigned u; __builtin_memcpy(&u, &f, 4);
    u += 0x7FFFu + ((u >> 16) & 1u);   // RNE
    return (ushort)(u >> 16);
}
__device__ __forceinline__ float fast_sigmoid(float x) {
    return __builtin_amdgcn_rcpf(1.f + __expf(-x));
}
__device__ __forceinline__ float fast_tanh(float x) {
    return 2.f * __builtin_amdgcn_rcpf(1.f + __expf(-2.f * x)) - 1.f;
}
// XOR swizzle: row stride 512B == 0 (mod 128B); spread rows across the 8
// 16B slots of the bank array. Keeps 16B alignment (only bits 4..6 flip).
__device__ __forceinline__ int swz(int row, int colB) {
    return row * ROWB + (colB ^ ((row & 7) << 4));
}

// Weight prep: f32 -> bf16.
// W1[m][k]: m<256 filter / m>=256 gate, k = tap*256 + in_ch.
// W2[m][i]: m<256 res / m>=256 skip.
__global__ __launch_bounds__(512)
void prep_w(const float* __restrict__ wf, const float* __restrict__ wg,
            const float* __restrict__ wr, const float* __restrict__ wsk,
            ushort* __restrict__ W1, ushort* __restrict__ W2) {
    int g = blockIdx.x * 512 + threadIdx.x;
    if (g < 512 * 64) {                       // W1: 512 rows x 64 threads (4 i each)
        int m = g >> 6, i0 = (g & 63) * 4;
        const float* src = (m < 256) ? wf + ((size_t)m << 9)
                                     : wg + ((size_t)(m - 256) << 9);
        f32x4 a = *(const f32x4*)&src[i0 * 2];
        f32x4 c = *(const f32x4*)&src[i0 * 2 + 4];
        u16x4 t0v = { f2b(a[0]), f2b(a[2]), f2b(c[0]), f2b(c[2]) };
        u16x4 t1v = { f2b(a[1]), f2b(a[3]), f2b(c[1]), f2b(c[3]) };
        *(u16x4*)&W1[(size_t)m * 512 + i0]       = t0v;   // tap 0 block
        *(u16x4*)&W1[(size_t)m * 512 + 256 + i0] = t1v;   // tap 1 block
    } else {                                  // W2: 512 rows x 64 threads
        int g2 = g - 512 * 64;
        int m = g2 >> 6, i0 = (g2 & 63) * 4;
        const float* src = (m < 256) ? wr + ((size_t)m << 8)
                                     : wsk + ((size_t)(m - 256) << 8);
        f32x4 a = *(const f32x4*)&src[i0];
        u16x4 o = { f2b(a[0]), f2b(a[1]), f2b(a[2]), f2b(a[3]) };
        *(u16x4*)&W2[(size_t)m * 256 + i0] = o;
    }
}

// 512 blocks x 1024 threads (16 waves). Wave w owns output channels
// [w*16, w*16+16) — filter rows + paired gate rows. acc[8][2] = 64 AGPR,
// distance-1 W prefetch (16 VGPR), xf read-pairs: total <= 128 regs/wave
// -> 4 waves/SIMD between barriers (2x the TLP of the acc[8][4] version).
// MFMA roles: A = x-fragment (M=16 tokens), B = W-fragment (N=16 out-ch)
// => D: row = quad*4+r = token, col = lane&15 = channel.
__global__ __launch_bounds__(1024, 4)
void fused_block(const float* __restrict__ x,
                 const ushort* __restrict__ W1, const ushort* __restrict__ W2,
                 const float* __restrict__ b_filt, const float* __restrict__ b_gate,
                 const float* __restrict__ b_res,  const float* __restrict__ b_skip,
                 float* __restrict__ out) {
    // rows 0..135: x[token][channel] bf16 swizzled (token = t0-8+row);
    // after GEMM1, rows 0..127 are reused for z[token][channel].
    __shared__ __align__(16) char lds[XROWS * ROWB];   // 69632 B

    const int tid = threadIdx.x;
    const int b  = blockIdx.x >> 5;           // 32 tiles per batch
    const int t0 = (blockIdx.x & 31) * NT;
    const float* X = x + (size_t)b * CH * TT;
    const int tg0 = t0 - HALO;

    // ---------------- stage x (f32 -> bf16, transposed, swizzled) ----------------
    {
        const int tc  = tid & 7;          // token chunk (4 tokens) within 32
        const int cp  = tid >> 3;         // channel pair 0..127
        const float* Xa = X + (size_t)(cp * 2) * TT;
        const float* Xb = Xa + TT;
        #pragma unroll
        for (int it = 0; it < 4; ++it) {  // rows 0..127
            int tg = tg0 + it * 32 + tc * 4;
            f32x4 va = (f32x4){0.f,0.f,0.f,0.f}, vb = va;
            if (tg >= 0) { va = *(const f32x4*)&Xa[tg]; vb = *(const f32x4*)&Xb[tg]; }
            #pragma unroll
            for (int e = 0; e < 4; ++e) {
                int row = it * 32 + tc * 4 + e;
                unsigned pk = (unsigned)f2b(va[e]) | ((unsigned)f2b(vb[e]) << 16);
                *(unsigned*)(lds + swz(row, cp * 4)) = pk;
            }
        }
        // tail rows 128..135 = tokens t0+120..t0+127 (always in range)
        int c = tid & 255, h = tid >> 8;  // h 0..3 -> 2 tokens each
        f32x2 v = *(const f32x2*)&X[(size_t)c * TT + tg0 + 128 + h * 2];
        #pragma unroll
        for (int e = 0; e < 2; ++e)
            *(ushort*)(lds + swz(128 + h * 2 + e, c * 2)) = f2b(v[e]);
    }
    __syncthreads();

    const int wv = tid >> 6, lane = tid & 63;
    const int l16 = lane & 15, quad = lane >> 4;
    const int ch16 = wv * 16;             // this wave's 16-channel stripe
    const ushort* W1F = W1 + (size_t)(ch16 + l16) * 512 + quad * 8;
    const ushort* W1G = W1F + (size_t)256 * 512;          // gate rows
    const ushort* W2F = W2 + (size_t)(ch16 + l16) * 256 + quad * 8;
    const ushort* W2G = W2F + (size_t)256 * 256;          // skip rows

    // ---------------- GEMM1: acc[token-tile][f/g] over K=512 ----------------
    f32x4 acc[8][2];
    #pragma unroll
    for (int i = 0; i < 8; ++i) { acc[i][0] = (f32x4){0.f,0.f,0.f,0.f};
                                  acc[i][1] = (f32x4){0.f,0.f,0.f,0.f}; }

    s16x8 wcF = *(const s16x8*)&W1F[0];
    s16x8 wcG = *(const s16x8*)&W1G[0];

    #pragma unroll
    for (int kq = 0; kq < 16; ++kq) {
        s16x8 wnF, wnG;
        if (kq < 15) {                       // distance-1 prefetch (L2-hot)
            wnF = *(const s16x8*)&W1F[(kq + 1) * 32];
            wnG = *(const s16x8*)&W1G[(kq + 1) * 32];
        }
        const int tap = kq >> 3, ci = kq & 7;
        #pragma unroll
        for (int g = 0; g < 4; ++g) {        // token-tiles in pairs
            s16x8 xf0 = *(const s16x8*)(lds + swz((2*g)   * 16 + l16 + 8 * tap, ci * 64 + quad * 16));
            s16x8 xf1 = *(const s16x8*)(lds + swz((2*g+1) * 16 + l16 + 8 * tap, ci * 64 + quad * 16));
            acc[2*g][0]   = __builtin_amdgcn_mfma_f32_16x16x32_bf16(xf0, wcF, acc[2*g][0],   0, 0, 0);
            acc[2*g][1]   = __builtin_amdgcn_mfma_f32_16x16x32_bf16(xf0, wcG, acc[2*g][1],   0, 0, 0);
            acc[2*g+1][0] = __builtin_amdgcn_mfma_f32_16x16x32_bf16(xf1, wcF, acc[2*g+1][0], 0, 0, 0);
            acc[2*g+1][1] = __builtin_amdgcn_mfma_f32_16x16x32_bf16(xf1, wcG, acc[2*g+1][1], 0, 0, 0);
        }
        if (kq < 15) { wcF = wnF; wcG = wnG; }
    }

    // preload GEMM2's first W fragments; L2 latency hides under barrier+act
    s16x8 wc2F = *(const s16x8*)&W2F[0];
    s16x8 wc2G = *(const s16x8*)&W2G[0];

    __syncthreads();   // all GEMM1 LDS reads done before z overwrites rows 0..127

    // ---------------- activations -> z (bf16) rows 0..127 ----------------
    {
        const int zc = ch16 + l16;
        const float bfv = b_filt[zc], bgv = b_gate[zc];
        #pragma unroll
        for (int tm = 0; tm < 8; ++tm) {
            #pragma unroll
            for (int r = 0; r < 4; ++r) {
                float fv = acc[tm][0][r] + bfv;
                float gv = acc[tm][1][r] + bgv;
                int row = tm * 16 + quad * 4 + r;
                *(ushort*)(lds + swz(row, zc * 2)) = f2b(fast_tanh(fv) * fast_sigmoid(gv));
            }
        }
    }
    __syncthreads();

    // ---------------- GEMM2 over K=256 (reuse acc registers) ----------------
    #pragma unroll
    for (int i = 0; i < 8; ++i) { acc[i][0] = (f32x4){0.f,0.f,0.f,0.f};
                                  acc[i][1] = (f32x4){0.f,0.f,0.f,0.f}; }

    #pragma unroll
    for (int kq = 0; kq < 8; ++kq) {
        s16x8 wn2F, wn2G;
        if (kq < 7) {
            wn2F = *(const s16x8*)&W2F[(kq + 1) * 32];
            wn2G = *(const s16x8*)&W2G[(kq + 1) * 32];
        }
        #pragma unroll
        for (int g = 0; g < 4; ++g) {
            s16x8 zf0 = *(const s16x8*)(lds + swz((2*g)   * 16 + l16, kq * 64 + quad * 16));
            s16x8 zf1 = *(const s16x8*)(lds + swz((2*g+1) * 16 + l16, kq * 64 + quad * 16));
            acc[2*g][0]   = __builtin_amdgcn_mfma_f32_16x16x32_bf16(zf0, wc2F, acc[2*g][0],   0, 0, 0);
            acc[2*g][1]   = __builtin_amdgcn_mfma_f32_16x16x32_bf16(zf0, wc2G, acc[2*g][1],   0, 0, 0);
            acc[2*g+1][0] = __builtin_amdgcn_mfma_f32_16x16x32_bf16(zf1, wc2F, acc[2*g+1][0], 0, 0, 0);
            acc[2*g+1][1] = __builtin_amdgcn_mfma_f32_16x16x32_bf16(zf1, wc2G, acc[2*g+1][1], 0, 0, 0);
        }
        if (kq < 7) { wc2F = wn2F; wc2G = wn2G; }
    }

    // ---------------- epilogue: vectorized f32x4 stores (plain, L2-combined) ----------------
    const size_t OUT1 = (size_t)NB * CH * TT;
    {
        const int ch = ch16 + l16;
        const float br = b_res[ch], bs = b_skip[ch];
        const float* Xc = X + (size_t)ch * TT + t0;
        float* O0 = out + ((size_t)(b * CH + ch)) * TT + t0;
        float* O1 = O0 + OUT1;
        #pragma unroll
        for (int tm = 0; tm < 8; ++tm) {
            const int ttk = tm * 16 + quad * 4;
            f32x4 xv = *(const f32x4*)&Xc[ttk];   // exact f32 x (L2-hot)
            f32x4 o0, o1;
            #pragma unroll
            for (int r = 0; r < 4; ++r) {
                o0[r] = xv[r] + acc[tm][0][r] + br;
                o1[r] = acc[tm][1][r] + bs;
            }
            *(f32x4*)&O0[ttk] = o0;
            *(f32x4*)&O1[ttk] = o1;
        }
    }
}

extern "C" void kernel_launch(void* const* d_in, const int* in_sizes, int n_in,
                              void* d_out, int out_size, void* d_ws, size_t ws_size,
                              hipStream_t stream) {
    const float* x   = (const float*)d_in[0];
    const float* wf  = (const float*)d_in[1];
    const float* bfi = (const float*)d_in[2];
    const float* wg  = (const float*)d_in[3];
    const float* bg  = (const float*)d_in[4];
    const float* wr  = (const float*)d_in[5];
    const float* br  = (const float*)d_in[6];
    const float* wsk = (const float*)d_in[7];
    const float* bs  = (const float*)d_in[8];

    ushort* W1 = (ushort*)d_ws;                  // 512*512 bf16
    ushort* W2 = W1 + 512 * 512;                 // 512*256 bf16

    prep_w<<<128, 512, 0, stream>>>(wf, wg, wr, wsk, W1, W2);

    const int nBlocks = NB * (TT / NT);          // 512
    fused_block<<<nBlocks, 1024, 0, stream>>>(x, W1, W2, bfi, bg, br, bs,
                                              (float*)d_out);
}